// Round 1
// baseline (427.931 us; speedup 1.0000x reference)
//
#include <hip/hip_runtime.h>
#include <math.h>

#define BB 16
#define HH 512
#define WW 512
#define IMGPIX (HH*WW)          // 262144 = 2^18
#define NPIX (BB*IMGPIX)        // 4194304
#define RAD 10
#define KS 21

// Params layout (floats) at P:
// [0]=alpha [1]=lam [2]=beta [3]=xi [4]=eta [5]=nu [6]=gamma [7]=omega
// [8..28] = gaussian k[0..20]
// [32..47] = per-image maxima (zeroed every launch)

__device__ __forceinline__ float sigmoidf_(float x) { return 1.0f / (1.0f + expf(-x)); }

__global__ void k_params(const float* a_raw, const float* l_raw, const float* lsig,
                         const float* lbeta, const float* lxi, const float* e_raw,
                         const float* n_raw, const float* lgam, const float* o_raw,
                         float* P)
{
    if (threadIdx.x != 0 || blockIdx.x != 0) return;
    float alpha = 0.6f + 1.4f * sigmoidf_(a_raw[0]);
    float lam   = 0.01f + 0.19f * sigmoidf_(l_raw[0]);
    float sigma = 0.5f + 4.5f * sigmoidf_(lsig[0]);
    float beta  = 1.0f + 4.0f * sigmoidf_(lbeta[0]);
    float xi    = 1.0f + 4.0f * sigmoidf_(lxi[0]);
    float eta   = sigmoidf_(e_raw[0]);
    float nu    = sigmoidf_(n_raw[0]);
    float gam   = 1.0f + 3.0f * sigmoidf_(lgam[0]);
    float omg   = sigmoidf_(o_raw[0]);
    P[0] = alpha; P[1] = lam; P[2] = beta; P[3] = xi;
    P[4] = eta;   P[5] = nu;  P[6] = gam; P[7] = omg;
    float kk[KS]; float s = 0.f;
    for (int i = 0; i < KS; ++i) {
        float c = (float)(i - RAD);
        kk[i] = expf(-c * c / (2.f * sigma * sigma + 1e-8f));
        s += kk[i];
    }
    float inv = 1.f / (s + 1e-8f);
    for (int i = 0; i < KS; ++i) P[8 + i] = kk[i] * inv;
    for (int i = 0; i < 16; ++i) P[32 + i] = 0.f;   // maxima slots
}

__global__ void k_blur_h(const float* __restrict__ src, float* __restrict__ dst,
                         const float* __restrict__ P)
{
    int idx = blockIdx.x * blockDim.x + threadIdx.x;
    if (idx >= NPIX) return;
    int x = idx & (WW - 1);
    int rowbase = idx - x;
    float acc = 0.f;
#pragma unroll
    for (int j = 0; j < KS; ++j) {
        int xx = x + j - RAD;
        xx = xx < 0 ? -xx : xx;
        xx = xx >= WW ? 2 * WW - 2 - xx : xx;
        acc = fmaf(P[8 + j], src[rowbase + xx], acc);
    }
    dst[idx] = acc;
}

__global__ void k_blur_v(const float* __restrict__ src, float* __restrict__ dst,
                         const float* __restrict__ P)
{
    int idx = blockIdx.x * blockDim.x + threadIdx.x;
    if (idx >= NPIX) return;
    int x = idx & (WW - 1);
    int y = (idx >> 9) & (HH - 1);
    int base = idx - y * WW - x;
    float acc = 0.f;
#pragma unroll
    for (int j = 0; j < KS; ++j) {
        int yy = y + j - RAD;
        yy = yy < 0 ? -yy : yy;
        yy = yy >= HH ? 2 * HH - 2 - yy : yy;
        acc = fmaf(P[8 + j], src[base + yy * WW + x], acc);
    }
    dst[idx] = acc;
}

__global__ void k_phi(const float* __restrict__ us, const float* __restrict__ lfd,
                      float* __restrict__ phi, const float* __restrict__ P)
{
    int idx = blockIdx.x * blockDim.x + threadIdx.x;
    if (idx >= NPIX) return;
    int x = idx & (WW - 1);
    int y = (idx >> 9) & (HH - 1);
    int base = idx - y * WW - x;
    int ym = (y == 0) ? 1 : y - 1;
    int yp = (y == HH - 1) ? HH - 2 : y + 1;
    int xm = (x == 0) ? 1 : x - 1;
    int xp = (x == WW - 1) ? WW - 2 : x + 1;
    float gys = (us[base + yp * WW + x] - us[base + ym * WW + x]) * 0.5f;
    float gxs = (us[base + y * WW + xp] - us[base + y * WW + xm]) * 0.5f;
    float g2 = fmaf(gxs, gxs, fmaf(gys, gys, 1e-8f));
    float ph = fminf(P[2] * sqrtf(P[3] / fmaf(P[4], g2, 1e-6f)), 10.f);
    float fw = fminf(fmaxf(1.f - P[7] * lfd[idx], 0.f), 1.f);
    phi[idx] = ph * fw;
}

__global__ void k_update(const float* __restrict__ u, const float* __restrict__ u0,
                         const float* __restrict__ phi, float* __restrict__ un,
                         const float* __restrict__ P)
{
    int idx = blockIdx.x * blockDim.x + threadIdx.x;
    if (idx >= NPIX) return;
    int x = idx & (WW - 1);
    int y = (idx >> 9) & (HH - 1);
    int base = idx - y * WW - x;
    int ym = (y == 0) ? 1 : y - 1;
    int yp = (y == HH - 1) ? HH - 2 : y + 1;
    int xm = (x == 0) ? 1 : x - 1;
    int xp = (x == WW - 1) ? WW - 2 : x + 1;
    float uc = u[idx];
    float uN = u[base + ym * WW + x];
    float uS = u[base + yp * WW + x];
    float uE = u[base + y * WW + xp];
    float uW = u[base + y * WW + xm];
    float gy = (uS - uN) * 0.5f;
    float gx = (uE - uW) * 0.5f;
    float lap = uN + uS + uE + uW - 4.f * uc;
    float gm = sqrtf(fmaf(gx, gx, fmaf(gy, gy, 1e-8f)));
    float s = gm * fabsf(lap);
    float psi = 1e-4f * sqrtf(fmaf(P[5], s * s * s, P[6]));
    float pN = phi[base + ym * WW + x];
    float pS = phi[base + yp * WW + x];
    float pE = phi[base + y * WW + xp];
    float pW = phi[base + y * WW + xm];
    float div = pN * (uN - uc) + pS * (uS - uc) + pE * (uE - uc) + pW * (uW - uc);
    float du = P[0] * psi * div - P[1] * (uc - u0[idx]);
    un[idx] = fminf(fmaxf(fmaf(0.1f, du, uc), 0.f), 1.f);
}

__global__ void k_res1(const float* __restrict__ img, const float* __restrict__ u,
                       float* __restrict__ r, float* __restrict__ Pmax)
{
    int t = threadIdx.x;
    int start = blockIdx.x * 1024;
    float m = 0.f;
#pragma unroll
    for (int i = 0; i < 4; ++i) {
        int idx = start + t + i * 256;
        float v = fabsf(img[idx] - u[idx]);
        r[idx] = v;
        m = fmaxf(m, v);
    }
    for (int off = 32; off > 0; off >>= 1) m = fmaxf(m, __shfl_down(m, off));
    __shared__ float sm[4];
    if ((t & 63) == 0) sm[t >> 6] = m;
    __syncthreads();
    if (t == 0) {
        m = fmaxf(fmaxf(sm[0], sm[1]), fmaxf(sm[2], sm[3]));
        atomicMax((unsigned int*)&Pmax[start >> 18], __float_as_uint(m));
    }
}

__global__ void k_res2(float* __restrict__ r, const float* __restrict__ Pmax)
{
    int idx = blockIdx.x * blockDim.x + threadIdx.x;
    if (idx >= NPIX) return;
    int b = idx >> 18;
    r[idx] = r[idx] / (Pmax[b] + 1e-8f);
}

extern "C" void kernel_launch(void* const* d_in, const int* in_sizes, int n_in,
                              void* d_out, int out_size, void* d_ws, size_t ws_size,
                              hipStream_t stream)
{
    const float* image = (const float*)d_in[0];
    const float* lfd   = (const float*)d_in[1];

    float* out_u = (float*)d_out;       // first NPIX floats
    float* out_r = out_u + NPIX;        // second NPIX floats

    float* tmp  = (float*)d_ws;         // NPIX floats (blur intermediate, then phi)
    float* usig = tmp + NPIX;           // NPIX floats
    float* uB   = usig + NPIX;          // NPIX floats (ping-pong buffer)
    float* P    = uB + NPIX;            // 64 floats params + maxima

    k_params<<<1, 64, 0, stream>>>((const float*)d_in[2], (const float*)d_in[3],
                                   (const float*)d_in[4], (const float*)d_in[5],
                                   (const float*)d_in[6], (const float*)d_in[7],
                                   (const float*)d_in[8], (const float*)d_in[9],
                                   (const float*)d_in[10], P);

    dim3 blk(256), grd(NPIX / 256);
    float* bufs[2] = { out_u, uB };
    for (int it = 0; it < 5; ++it) {
        const float* usrc = (it == 0) ? image : bufs[(it + 1) & 1];
        float* udst = bufs[it & 1];
        k_blur_h<<<grd, blk, 0, stream>>>(usrc, tmp, P);
        k_blur_v<<<grd, blk, 0, stream>>>(tmp, usig, P);
        k_phi<<<grd, blk, 0, stream>>>(usig, lfd, tmp, P);
        k_update<<<grd, blk, 0, stream>>>(usrc, image, tmp, udst, P);
    }
    // final u is in out_u (it=4 wrote bufs[0])

    k_res1<<<NPIX / 1024, 256, 0, stream>>>(image, out_u, out_r, P + 32);
    k_res2<<<grd, blk, 0, stream>>>(out_r, P + 32);
}

// Round 2
// 237.288 us; speedup vs baseline: 1.8034x; 1.8034x over previous
//
#include <hip/hip_runtime.h>
#include <math.h>

#define HH 512
#define WW 512
#define IMGPIX (HH*WW)          // 2^18
#define NPIX (16*IMGPIX)
#define RAD 10
#define KS 21
#define TX 64
#define TY 32

// Params layout (floats) at P:
// [0]=alpha [1]=lam [2]=beta [3]=xi [4]=eta [5]=nu [6]=gamma [7]=omega
// [8..28] = gaussian weights
// [64 + 32*i] = per-image max slot i (128B apart, zeroed every launch)

__device__ __forceinline__ int refl(int v, int n) {
    v = v < 0 ? -v : v;
    return v >= n ? 2*n - 2 - v : v;
}
__device__ __forceinline__ float sigmoidf_(float x) { return 1.0f / (1.0f + expf(-x)); }

__global__ void k_params(const float* a_raw, const float* l_raw, const float* lsig,
                         const float* lbeta, const float* lxi, const float* e_raw,
                         const float* n_raw, const float* lgam, const float* o_raw,
                         float* P)
{
    if (threadIdx.x != 0 || blockIdx.x != 0) return;
    float sigma = 0.5f + 4.5f * sigmoidf_(lsig[0]);
    P[0] = 0.6f + 1.4f * sigmoidf_(a_raw[0]);
    P[1] = 0.01f + 0.19f * sigmoidf_(l_raw[0]);
    P[2] = 1.0f + 4.0f * sigmoidf_(lbeta[0]);
    P[3] = 1.0f + 4.0f * sigmoidf_(lxi[0]);
    P[4] = sigmoidf_(e_raw[0]);
    P[5] = sigmoidf_(n_raw[0]);
    P[6] = 1.0f + 3.0f * sigmoidf_(lgam[0]);
    P[7] = sigmoidf_(o_raw[0]);
    float kk[KS]; float s = 0.f;
    for (int i = 0; i < KS; ++i) {
        float c = (float)(i - RAD);
        kk[i] = expf(-c * c / (2.f * sigma * sigma + 1e-8f));
        s += kk[i];
    }
    float inv = 1.f / (s + 1e-8f);
    for (int i = 0; i < KS; ++i) P[8 + i] = kk[i] * inv;
    for (int i = 0; i < 16; ++i) P[64 + 32*i] = 0.f;
}

// One full diffusion step, fully fused. Tile TY=32 x TX=64 per block (256 thr).
// sh: h-blur rows y0-12..y0+43 (56) x cols x0-2..x0+65 (68), stride 72
// su: usig rows y0-2..y0+33 (36) x cols (68)
// ut: u rows y0-1..y0+32 (34) x cols x0-1..x0+64 (66)
// pt: phi (34x66), aliases sh (after v-blur consumed it)
__global__ __launch_bounds__(256)
void k_iter(const float* __restrict__ src, const float* __restrict__ img,
            const float* __restrict__ lfd, float* __restrict__ dst,
            const float* __restrict__ P, float* Pmax, int do_max)
{
    __shared__ __attribute__((aligned(16))) float sh[56][72];
    __shared__ float su[36][72];
    __shared__ float ut[34][72];
    __shared__ float red[4];
    float (*pt)[72] = sh;

    const int tid = threadIdx.x;
    const int x0 = blockIdx.x * TX;
    const int y0 = blockIdx.y * TY;
    const int b  = blockIdx.z;
    const float* sb = src + (b << 18);
    const float* ib = img + (b << 18);
    const float* lb = lfd + (b << 18);
    float* db = dst + (b << 18);

    float kw[KS];
#pragma unroll
    for (int j = 0; j < KS; ++j) kw[j] = P[8 + j];
    const float alpha = P[0], lam = P[1], beta = P[2], xi = P[3];
    const float eta = P[4], nu = P[5], gam = P[6], omg = P[7];

    // --- load u tile (34 x 66), reflect ---
#pragma unroll
    for (int p = 0; p < 9; ++p) {
        int i = tid + p * 256;
        if (i < 34 * 66) {
            int r = i / 66, c = i - r * 66;
            ut[r][c] = sb[refl(y0 - 1 + r, HH) * WW + refl(x0 - 1 + c, WW)];
        }
    }
    // --- horizontal blur: 56 rows x 17 groups-of-4 ---
#pragma unroll
    for (int p = 0; p < 4; ++p) {
        int i = tid + p * 256;
        if (i < 56 * 17) {
            int hr = i / 17, g = i - hr * 17;
            const float* row = sb + refl(y0 - 12 + hr, HH) * WW;
            int gxs = x0 - 12 + 4 * g;   // window [gxs, gxs+23], outputs cols gxs+10..gxs+13
            float w[24];
            if (gxs >= 0 && gxs + 23 < WW) {
                const float4* p4 = (const float4*)(row + gxs);
#pragma unroll
                for (int q = 0; q < 6; ++q) {
                    float4 v = p4[q];
                    w[4*q] = v.x; w[4*q+1] = v.y; w[4*q+2] = v.z; w[4*q+3] = v.w;
                }
            } else {
#pragma unroll
                for (int q = 0; q < 24; ++q) w[q] = row[refl(gxs + q, WW)];
            }
            float a0 = 0.f, a1 = 0.f, a2 = 0.f, a3 = 0.f;
#pragma unroll
            for (int j = 0; j < KS; ++j) {
                a0 = fmaf(kw[j], w[j],     a0);
                a1 = fmaf(kw[j], w[j + 1], a1);
                a2 = fmaf(kw[j], w[j + 2], a2);
                a3 = fmaf(kw[j], w[j + 3], a3);
            }
            float4 o; o.x = a0; o.y = a1; o.z = a2; o.w = a3;
            *(float4*)&sh[hr][4 * g] = o;
        }
    }
    __syncthreads();
    // --- vertical blur: su (36 rows x 68 cols), 4 rows per thread-item ---
#pragma unroll
    for (int p = 0; p < 3; ++p) {
        int i = tid + p * 256;
        if (i < 9 * 68) {
            int rg = i / 68, c = i - rg * 68;
            int r0 = rg * 4;
            float a0 = 0.f, a1 = 0.f, a2 = 0.f, a3 = 0.f;
#pragma unroll
            for (int q = 0; q < 24; ++q) {
                float s = sh[r0 + q][c];
                if (q <= 20)           a0 = fmaf(kw[q],     s, a0);
                if (q >= 1 && q <= 21) a1 = fmaf(kw[q - 1], s, a1);
                if (q >= 2 && q <= 22) a2 = fmaf(kw[q - 2], s, a2);
                if (q >= 3)            a3 = fmaf(kw[q - 3], s, a3);
            }
            su[r0][c] = a0; su[r0+1][c] = a1; su[r0+2][c] = a2; su[r0+3][c] = a3;
        }
    }
    __syncthreads();
    // --- phi into pt (34 x 66); pt aliases sh (safe: sh fully consumed) ---
#pragma unroll
    for (int p = 0; p < 9; ++p) {
        int i = tid + p * 256;
        if (i < 34 * 66) {
            int r = i / 66, c = i - r * 66;
            float gys = (su[r + 2][c + 1] - su[r][c + 1]) * 0.5f;
            float gxs = (su[r + 1][c + 2] - su[r + 1][c]) * 0.5f;
            float g2 = fmaf(gxs, gxs, fmaf(gys, gys, 1e-8f));
            float ph = fminf(beta * sqrtf(xi / fmaf(eta, g2, 1e-6f)), 10.f);
            float lv = lb[refl(y0 - 1 + r, HH) * WW + refl(x0 - 1 + c, WW)];
            float fw = fminf(fmaxf(1.f - omg * lv, 0.f), 1.f);
            pt[r][c] = ph * fw;
        }
    }
    __syncthreads();
    // --- final stencil update: 32 x 64 outputs ---
    const int c = tid & 63, r0 = tid >> 6;
    float mymax = 0.f;
#pragma unroll
    for (int p = 0; p < 8; ++p) {
        int r = r0 + p * 4;
        float uc = ut[r + 1][c + 1];
        float uN = ut[r][c + 1],     uS = ut[r + 2][c + 1];
        float uE = ut[r + 1][c + 2], uW = ut[r + 1][c];
        float gy = (uS - uN) * 0.5f, gx = (uE - uW) * 0.5f;
        float lap = uN + uS + uE + uW - 4.f * uc;
        float gm = sqrtf(fmaf(gx, gx, fmaf(gy, gy, 1e-8f)));
        float s = gm * fabsf(lap);
        float psi = 1e-4f * sqrtf(fmaf(nu, s * s * s, gam));
        float pN = pt[r][c + 1],     pS = pt[r + 2][c + 1];
        float pE = pt[r + 1][c + 2], pW = pt[r + 1][c];
        float dv = pN * (uN - uc) + pS * (uS - uc) + pE * (uE - uc) + pW * (uW - uc);
        int gidx = (y0 + r) * WW + x0 + c;
        float u0v = ib[gidx];
        float du = alpha * psi * dv - lam * (uc - u0v);
        float un = fminf(fmaxf(fmaf(0.1f, du, uc), 0.f), 1.f);
        db[gidx] = un;
        mymax = fmaxf(mymax, fabsf(u0v - un));
    }
    if (do_max) {
#pragma unroll
        for (int off = 32; off; off >>= 1) mymax = fmaxf(mymax, __shfl_down(mymax, off));
        if ((tid & 63) == 0) red[tid >> 6] = mymax;
        __syncthreads();
        if (tid == 0) {
            float m = fmaxf(fmaxf(red[0], red[1]), fmaxf(red[2], red[3]));
            atomicMax((unsigned int*)(Pmax + 32 * b), __float_as_uint(m));
        }
    }
}

__global__ void k_res2(const float* __restrict__ img, const float* __restrict__ u,
                       float* __restrict__ r, const float* __restrict__ Pmax)
{
    int i = blockIdx.x * 256 + threadIdx.x;      // i indexes float4s, NPIX/4 total
    int b = i >> 16;                              // (4i)>>18
    float inv = 1.f / (Pmax[32 * b] + 1e-8f);
    float4 a = ((const float4*)img)[i];
    float4 c = ((const float4*)u)[i];
    float4 o;
    o.x = fabsf(a.x - c.x) * inv;
    o.y = fabsf(a.y - c.y) * inv;
    o.z = fabsf(a.z - c.z) * inv;
    o.w = fabsf(a.w - c.w) * inv;
    ((float4*)r)[i] = o;
}

extern "C" void kernel_launch(void* const* d_in, const int* in_sizes, int n_in,
                              void* d_out, int out_size, void* d_ws, size_t ws_size,
                              hipStream_t stream)
{
    const float* image = (const float*)d_in[0];
    const float* lfd   = (const float*)d_in[1];

    float* out_u = (float*)d_out;
    float* out_r = out_u + NPIX;

    float* uB = (float*)d_ws;            // NPIX floats ping-pong
    float* P  = uB + NPIX;               // 64 + 512 floats

    k_params<<<1, 64, 0, stream>>>((const float*)d_in[2], (const float*)d_in[3],
                                   (const float*)d_in[4], (const float*)d_in[5],
                                   (const float*)d_in[6], (const float*)d_in[7],
                                   (const float*)d_in[8], (const float*)d_in[9],
                                   (const float*)d_in[10], P);

    dim3 grd(WW / TX, HH / TY, 16), blk(256);
    float* Pmax = P + 64;
    for (int it = 0; it < 5; ++it) {
        const float* src = (it == 0) ? image : ((it & 1) ? out_u : uB);
        float* dst = (it & 1) ? uB : out_u;
        k_iter<<<grd, blk, 0, stream>>>(src, image, lfd, dst, P, Pmax, it == 4 ? 1 : 0);
    }
    k_res2<<<NPIX / 1024, 256, 0, stream>>>(image, out_u, out_r, Pmax);
}

// Round 3
// 208.988 us; speedup vs baseline: 2.0476x; 1.1354x over previous
//
#include <hip/hip_runtime.h>
#include <math.h>

#define HH 512
#define WW 512
#define NPIX (16*HH*WW)
#define RAD 10
#define KS 21
#define TX 64
#define TY 32

__device__ __forceinline__ int refl(int v, int n){ v = v < 0 ? -v : v; return v >= n ? 2*n - 2 - v : v; }
__device__ __forceinline__ float sigm(float x){ return 1.f/(1.f+expf(-x)); }

// P layout: [0]=alpha [1]=lam [2]=beta*sqrt(xi) [3]=eta [4]=nu [5]=gamma [6]=omega
// [8..28]=gauss weights, [64+32*i]=per-image max slots (zeroed every launch)
__global__ void k_params(const float* a_raw, const float* l_raw, const float* lsig,
                         const float* lbeta, const float* lxi, const float* e_raw,
                         const float* n_raw, const float* lgam, const float* o_raw,
                         float* P)
{
    if (threadIdx.x || blockIdx.x) return;
    float sigma = 0.5f + 4.5f*sigm(lsig[0]);
    float beta  = 1.f + 4.f*sigm(lbeta[0]);
    float xi    = 1.f + 4.f*sigm(lxi[0]);
    P[0] = 0.6f + 1.4f*sigm(a_raw[0]);
    P[1] = 0.01f + 0.19f*sigm(l_raw[0]);
    P[2] = beta*sqrtf(xi);
    P[3] = sigm(e_raw[0]);
    P[4] = sigm(n_raw[0]);
    P[5] = 1.f + 3.f*sigm(lgam[0]);
    P[6] = sigm(o_raw[0]);
    float kk[KS], s = 0.f;
    for (int i = 0; i < KS; ++i){ float c = (float)(i-RAD); kk[i] = expf(-c*c/(2.f*sigma*sigma+1e-8f)); s += kk[i]; }
    float inv = 1.f/(s+1e-8f);
    for (int i = 0; i < KS; ++i) P[8+i] = kk[i]*inv;
    for (int i = 0; i < 16; ++i) P[64+32*i] = 0.f;
}

// Horizontal blur, exactly once per pixel. 4 px/thread, aligned float4 I/O.
__global__ __launch_bounds__(256)
void k_hblur(const float* __restrict__ src, float* __restrict__ dst,
             const float* __restrict__ P)
{
    float kw[KS];
#pragma unroll
    for (int j = 0; j < KS; ++j) kw[j] = P[8+j];
    int i = blockIdx.x*256 + threadIdx.x;   // float4-group index
    int m = i & 127;
    int row = i >> 7;                        // 0..8191 (16*512 rows)
    const float* rp = src + row*WW;
    float l[32];
    if (m >= 3 && m <= 123){
        const float4* p4 = (const float4*)(rp + 4*m - 12);
#pragma unroll
        for (int q = 0; q < 8; ++q){ float4 v = p4[q]; l[4*q]=v.x; l[4*q+1]=v.y; l[4*q+2]=v.z; l[4*q+3]=v.w; }
    } else {
#pragma unroll
        for (int q = 0; q < 32; ++q) l[q] = rp[refl(4*m-12+q, WW)];
    }
    float a0=0.f, a1=0.f, a2=0.f, a3=0.f;
#pragma unroll
    for (int j = 0; j < KS; ++j){
        float k = kw[j];
        a0 = fmaf(k, l[j+2], a0);
        a1 = fmaf(k, l[j+3], a1);
        a2 = fmaf(k, l[j+4], a2);
        a3 = fmaf(k, l[j+5], a3);
    }
    float4 o; o.x=a0; o.y=a1; o.z=a2; o.w=a3;
    *(float4*)(dst + row*WW + 4*m) = o;
}

// Fused v-blur + phi + update (+ final-iter residual & max).
__global__ __launch_bounds__(256, 6)
void k_fused(const float* __restrict__ u, const float* __restrict__ tmp,
             const float* __restrict__ img, const float* __restrict__ lfd,
             float* __restrict__ dst, float* __restrict__ resid,
             const float* __restrict__ P, float* Pmax, int do_max)
{
    __shared__ float su[36][68];
    __shared__ float pt[34][68];
    __shared__ float red[4];
    const int tid = threadIdx.x;
    const int x0 = blockIdx.x*TX, y0 = blockIdx.y*TY, b = blockIdx.z;
    const float* tb = tmp + (b<<18);
    const float* ub = u   + (b<<18);
    const float* ib = img + (b<<18);
    const float* lb = lfd + (b<<18);
    float* db = dst + (b<<18);

    float kw[KS];
#pragma unroll
    for (int j = 0; j < KS; ++j) kw[j] = P[8+j];
    const float alpha=P[0], lam=P[1], bsx=P[2], eta=P[3], nu=P[4], gam=P[5], omg=P[6];
    const bool yint = (y0 >= 32) && (y0 <= 448);
    const bool xint = (x0 >= 64) && (x0 <= 384);

    // --- vertical blur from global tmp: 9 row-groups x 68 cols = 612 items ---
#pragma unroll
    for (int p = 0; p < 3; ++p){
        int i = tid + p*256;
        if (i < 612){
            int rg = i/68, c = i - rg*68;
            int xc = x0 - 2 + c;
            if (!xint) xc = refl(xc, WW);
            int yb = y0 - 12 + rg*4;
            float w[24];
            if (yint){
                const float* cp = tb + yb*WW + xc;
#pragma unroll
                for (int q = 0; q < 24; ++q) w[q] = cp[q*WW];
            } else {
#pragma unroll
                for (int q = 0; q < 24; ++q) w[q] = tb[refl(yb+q, HH)*WW + xc];
            }
            float a0=0.f, a1=0.f, a2=0.f, a3=0.f;
#pragma unroll
            for (int j = 0; j < KS; ++j){
                float k = kw[j];
                a0 = fmaf(k, w[j],   a0);
                a1 = fmaf(k, w[j+1], a1);
                a2 = fmaf(k, w[j+2], a2);
                a3 = fmaf(k, w[j+3], a3);
            }
            int r0 = rg*4;
            su[r0][c]=a0; su[r0+1][c]=a1; su[r0+2][c]=a2; su[r0+3][c]=a3;
        }
    }
    __syncthreads();

    // --- phi: 34 x 66 ---
#pragma unroll
    for (int p = 0; p < 9; ++p){
        int i = tid + p*256;
        if (i < 2244){
            int r = i/66, c = i - r*66;
            float gys = (su[r+2][c+1] - su[r][c+1])*0.5f;
            float gxs = (su[r+1][c+2] - su[r+1][c])*0.5f;
            float d = fmaf(eta, fmaf(gxs,gxs, fmaf(gys,gys, 1e-8f)), 1e-6f);
            float ph = fminf(bsx*rsqrtf(d), 10.f);
            int py = y0-1+r, px = x0-1+c;
            if (!yint) py = refl(py, HH);
            if (!xint) px = refl(px, WW);
            float fw = fminf(fmaxf(1.f - omg*lb[py*WW+px], 0.f), 1.f);
            pt[r][c] = ph*fw;
        }
    }
    __syncthreads();

    // --- update: 32 x 64 outputs, u read from global (L2/L3-hot) ---
    const int c = tid & 63, r00 = tid >> 6;
    const int gx = x0 + c;
    int xm = gx-1, xp = gx+1;
    if (!xint){ xm = refl(xm, WW); xp = refl(xp, WW); }
    float mymax = 0.f;
#pragma unroll
    for (int p = 0; p < 8; ++p){
        int r = r00 + p*4;
        int gy = y0 + r;
        int ym = gy-1, yp = gy+1;
        if (!yint){ ym = refl(ym, HH); yp = refl(yp, HH); }
        int idx = gy*WW + gx;
        float uc = ub[idx];
        float uN = ub[ym*WW + gx];
        float uS = ub[yp*WW + gx];
        float uE = ub[gy*WW + xp];
        float uW = ub[gy*WW + xm];
        float gyv = (uS-uN)*0.5f, gxv = (uE-uW)*0.5f;
        float lap = uN+uS+uE+uW - 4.f*uc;
        float gm = sqrtf(fmaf(gxv,gxv, fmaf(gyv,gyv, 1e-8f)));
        float s = gm*fabsf(lap);
        float psi = 1e-4f*sqrtf(fmaf(nu, s*s*s, gam));
        float pN = pt[r][c+1], pS = pt[r+2][c+1], pE = pt[r+1][c+2], pW = pt[r+1][c];
        float dv = pN*(uN-uc) + pS*(uS-uc) + pE*(uE-uc) + pW*(uW-uc);
        float u0v = ib[idx];
        float du = alpha*psi*dv - lam*(uc-u0v);
        float un = fminf(fmaxf(fmaf(0.1f, du, uc), 0.f), 1.f);
        db[idx] = un;
        if (do_max){
            float v = fabsf(u0v - un);
            resid[(b<<18)+idx] = v;
            mymax = fmaxf(mymax, v);
        }
    }
    if (do_max){
#pragma unroll
        for (int off = 32; off; off >>= 1) mymax = fmaxf(mymax, __shfl_down(mymax, off));
        if ((tid & 63) == 0) red[tid>>6] = mymax;
        __syncthreads();
        if (tid == 0){
            float m = fmaxf(fmaxf(red[0],red[1]), fmaxf(red[2],red[3]));
            atomicMax((unsigned int*)(Pmax + 32*b), __float_as_uint(m));
        }
    }
}

// in-place normalize of residual
__global__ void k_res2(float* __restrict__ r, const float* __restrict__ Pmax)
{
    int i = blockIdx.x*256 + threadIdx.x;   // float4 index
    int b = i >> 16;
    float inv = 1.f/(Pmax[32*b] + 1e-8f);
    float4 v = ((const float4*)r)[i];
    v.x *= inv; v.y *= inv; v.z *= inv; v.w *= inv;
    ((float4*)r)[i] = v;
}

extern "C" void kernel_launch(void* const* d_in, const int* in_sizes, int n_in,
                              void* d_out, int out_size, void* d_ws, size_t ws_size,
                              hipStream_t stream)
{
    const float* image = (const float*)d_in[0];
    const float* lfd   = (const float*)d_in[1];

    float* out_u = (float*)d_out;
    float* out_r = out_u + NPIX;

    float* tmp = (float*)d_ws;           // NPIX: h-blur output
    float* uB  = tmp + NPIX;             // NPIX: ping-pong
    float* P   = uB + NPIX;              // params + max slots

    k_params<<<1, 64, 0, stream>>>((const float*)d_in[2], (const float*)d_in[3],
                                   (const float*)d_in[4], (const float*)d_in[5],
                                   (const float*)d_in[6], (const float*)d_in[7],
                                   (const float*)d_in[8], (const float*)d_in[9],
                                   (const float*)d_in[10], P);

    dim3 grd(WW/TX, HH/TY, 16), blk(256);
    float* Pmax = P + 64;
    for (int it = 0; it < 5; ++it){
        const float* src = (it == 0) ? image : ((it & 1) ? out_u : uB);
        float* dstp = (it & 1) ? uB : out_u;
        k_hblur<<<4096, 256, 0, stream>>>(src, tmp, P);
        k_fused<<<grd, blk, 0, stream>>>(src, tmp, image, lfd, dstp, out_r, P, Pmax, it == 4 ? 1 : 0);
    }
    k_res2<<<NPIX/1024, 256, 0, stream>>>(out_r, Pmax);
}